// Round 1
// baseline (528.974 us; speedup 1.0000x reference)
//
#include <hip/hip_runtime.h>
#include <hip/hip_bf16.h>

#define B_ 2
#define S_ 2048
#define E_ 1024
#define H_ 16
#define D_ 64
#define M_ 4096  // B_*S_

typedef __bf16 bf16_t;
typedef bf16_t bf16x8 __attribute__((ext_vector_type(8)));
typedef float f32x4 __attribute__((ext_vector_type(4)));

__device__ __forceinline__ f32x4 mfma16(bf16x8 a, bf16x8 b, f32x4 c) {
    return __builtin_amdgcn_mfma_f32_16x16x32_bf16(a, b, c, 0, 0, 0);
}
__device__ __forceinline__ unsigned short f2bf(float f) {
    unsigned int u = __float_as_uint(f);
    unsigned int r = (u + 0x7fffu + ((u >> 16) & 1u)) >> 16;
    return (unsigned short)r;
}
__device__ __forceinline__ float bf2f(unsigned short s) {
    return __uint_as_float(((unsigned int)s) << 16);
}
// order-preserving float<->uint for atomic min/max
__device__ __forceinline__ unsigned int fenc(float x) {
    unsigned int u = __float_as_uint(x);
    return (u & 0x80000000u) ? ~u : (u | 0x80000000u);
}
__device__ __forceinline__ float fdec(unsigned int u) {
    return __uint_as_float((u & 0x80000000u) ? (u ^ 0x80000000u) : ~u);
}

__global__ void k_init(unsigned int* mm) {
    int t = threadIdx.x;
    if (t < 2) { mm[t * 2] = 0xFFFFFFFFu; mm[t * 2 + 1] = 0u; }
}

__global__ __launch_bounds__(256) void k_cast(const float* __restrict__ src,
                                              unsigned short* __restrict__ dst, int n8) {
    int i = blockIdx.x * 256 + threadIdx.x;
    if (i >= n8) return;
    const float4* s4 = (const float4*)src;
    float4 a = s4[2 * i], c = s4[2 * i + 1];
    uint4 o;
    o.x = (unsigned int)f2bf(a.x) | ((unsigned int)f2bf(a.y) << 16);
    o.y = (unsigned int)f2bf(a.z) | ((unsigned int)f2bf(a.w) << 16);
    o.z = (unsigned int)f2bf(c.x) | ((unsigned int)f2bf(c.y) << 16);
    o.w = (unsigned int)f2bf(c.z) | ((unsigned int)f2bf(c.w) << 16);
    ((uint4*)dst)[i] = o;
}

// C[m][n] = sum_k A[m][k]*B[n][k] + bias[n].  A:[4096][1024] bf16, B:[1024][1024] bf16 (row=n, contiguous k).
// MODE 0: write bf16 v in [b][h][s][d] layout + per-batch min/max atomics.
// MODE 1: write fp32 to outf[m][n].
template <int MODE>
__global__ __launch_bounds__(256) void k_gemm(const unsigned short* __restrict__ A,
                                              const unsigned short* __restrict__ Bm,
                                              const float* __restrict__ bias,
                                              unsigned short* __restrict__ outb,
                                              float* __restrict__ outf,
                                              unsigned int* __restrict__ mm) {
    const int K = 1024;
    int tid = threadIdx.x, lane = tid & 63, w = tid >> 6;
    int wm = w >> 1, wn = w & 1;
    int m0 = blockIdx.x * 128 + wm * 64, n0 = blockIdx.y * 128 + wn * 64;
    int lrow = lane & 15, lgrp = lane >> 4;
    f32x4 acc[4][4];
    for (int i = 0; i < 4; ++i)
        for (int j = 0; j < 4; ++j) acc[i][j] = (f32x4){0.f, 0.f, 0.f, 0.f};
    const unsigned short* Ap = A + (size_t)(m0 + lrow) * K + lgrp * 8;
    const unsigned short* Bp = Bm + (size_t)(n0 + lrow) * K + lgrp * 8;
    for (int k = 0; k < K; k += 32) {
        bf16x8 af[4], bfr[4];
#pragma unroll
        for (int t = 0; t < 4; ++t) af[t] = *reinterpret_cast<const bf16x8*>(Ap + (size_t)t * 16 * K + k);
#pragma unroll
        for (int t = 0; t < 4; ++t) bfr[t] = *reinterpret_cast<const bf16x8*>(Bp + (size_t)t * 16 * K + k);
#pragma unroll
        for (int mt = 0; mt < 4; ++mt)
#pragma unroll
            for (int nt = 0; nt < 4; ++nt) acc[mt][nt] = mfma16(af[mt], bfr[nt], acc[mt][nt]);
    }
    float vmin = 1e30f, vmax = -1e30f;
#pragma unroll
    for (int nt = 0; nt < 4; ++nt) {
        float bs = bias[n0 + nt * 16 + lrow];
#pragma unroll
        for (int mt = 0; mt < 4; ++mt)
#pragma unroll
            for (int r = 0; r < 4; ++r) {
                int mrow = m0 + mt * 16 + lgrp * 4 + r;
                int ncol = n0 + nt * 16 + lrow;
                float val = acc[mt][nt][r] + bs;
                if constexpr (MODE == 0) {
                    vmin = fminf(vmin, val);
                    vmax = fmaxf(vmax, val);
                    int b = mrow >> 11, s = mrow & 2047, h = ncol >> 6, d = ncol & 63;
                    outb[(size_t)((b * 16 + h) * 2048 + s) * 64 + d] = f2bf(val);
                } else {
                    outf[(size_t)mrow * 1024 + ncol] = val;
                }
            }
    }
    if constexpr (MODE == 0) {
#pragma unroll
        for (int m = 1; m < 64; m <<= 1) {
            vmin = fminf(vmin, __shfl_xor(vmin, m));
            vmax = fmaxf(vmax, __shfl_xor(vmax, m));
        }
        if (lane == 0) {
            int b = m0 >> 11;
            atomicMin(&mm[b * 2], fenc(vmin));
            atomicMax(&mm[b * 2 + 1], fenc(vmax));
        }
    }
}

// v_bf [bh][s][64] -> vt [bh][64][s], 64x64 tiles via LDS
__global__ __launch_bounds__(256) void k_transpose(const unsigned short* __restrict__ vbuf,
                                                   unsigned short* __restrict__ vt) {
    __shared__ __align__(16) unsigned short tile[64][72];
    int bh = blockIdx.y, st = blockIdx.x;
    int t = threadIdx.x;
    int row = t >> 2, cb = (t & 3) * 16;
    const unsigned short* src = vbuf + (size_t)bh * S_ * 64 + (size_t)st * 64 * 64;
    *(uint4*)&tile[row][cb] = *(const uint4*)(src + row * 64 + cb);
    *(uint4*)&tile[row][cb + 8] = *(const uint4*)(src + row * 64 + cb + 8);
    __syncthreads();
    int d = row, sb = cb;
    unsigned short tmp[16];
#pragma unroll
    for (int i = 0; i < 16; ++i) tmp[i] = tile[sb + i][d];
    unsigned short* dst = vt + (size_t)bh * 64 * S_ + (size_t)d * S_ + st * 64 + sb;
    *(uint4*)dst = *(uint4*)&tmp[0];
    *(uint4*)(dst + 8) = *(uint4*)&tmp[8];
}

// per (b,h): lane=d, serial prefix scan over s; inv = 1/((prefix_mean(v)-vmin)*ir + 0.5)
__global__ void k_scan(const unsigned short* __restrict__ vb, float* __restrict__ inv,
                       const unsigned int* __restrict__ mm) {
    int bh = blockIdx.x;
    int lane = threadIdx.x;
    int b = bh >> 4;
    float vmin = fdec(mm[b * 2]), vmax = fdec(mm[b * 2 + 1]);
    float ir = 1.0f / (vmax - vmin + 1e-8f);
    const unsigned short* src = vb + (size_t)bh * S_ * 64 + lane;
    float* dst = inv + (size_t)bh * S_ * 64 + lane;
    float acc = 0.f;
#pragma unroll 8
    for (int s = 0; s < S_; ++s) {
        acc += bf2f(src[(size_t)s * 64]);
        float phi = acc / (float)(s + 1);
        float den = (phi - vmin) * ir + 0.5f;
        dst[(size_t)s * 64] = 1.0f / den;
    }
}

// gene' = inv / rowsum(inv) * ir   (inv_range folded in; min-shift cancels in softmax)
__global__ __launch_bounds__(256) void k_rowsum(const float* __restrict__ invd,
                                                unsigned short* __restrict__ gene,
                                                const unsigned int* __restrict__ mm) {
    int row = blockIdx.x * 4 + (threadIdx.x >> 6);
    int lane = threadIdx.x & 63;
    int b = row >> 15;
    float vmin = fdec(mm[b * 2]), vmax = fdec(mm[b * 2 + 1]);
    float ir = 1.0f / (vmax - vmin + 1e-8f);
    float xv = invd[(size_t)row * 64 + lane];
    float s = xv;
#pragma unroll
    for (int m = 1; m < 64; m <<= 1) s += __shfl_xor(s, m);
    gene[(size_t)row * 64 + lane] = f2bf(xv / s * ir);
}

// flash-style: 1 wave = 16 query rows; key tiles of 32; online softmax; P via per-wave LDS.
__global__ __launch_bounds__(256) void k_attn(const unsigned short* __restrict__ gene,
                                              const unsigned short* __restrict__ vb,
                                              const unsigned short* __restrict__ vt,
                                              unsigned short* __restrict__ attn_out) {
    __shared__ __align__(16) unsigned short plds[4][16 * 40];
    int tid = threadIdx.x;
    int w = tid >> 6, lane = tid & 63;
    int W = blockIdx.x * 4 + w;
    int bh = W >> 7;
    int it = W & 127;
    int i0 = it * 16;
    int lrow = lane & 15, lgrp = lane >> 4;
    const unsigned short* gbase = gene + (size_t)bh * S_ * 64;
    const unsigned short* vbase = vb + (size_t)bh * S_ * 64;
    const unsigned short* tbase = vt + (size_t)bh * 64 * S_;
    bf16x8 ga0 = *reinterpret_cast<const bf16x8*>(gbase + (size_t)(i0 + lrow) * 64 + lgrp * 8);
    bf16x8 ga1 = *reinterpret_cast<const bf16x8*>(gbase + (size_t)(i0 + lrow) * 64 + 32 + lgrp * 8);
    f32x4 acc[4];
    for (int n = 0; n < 4; ++n) acc[n] = (f32x4){0.f, 0.f, 0.f, 0.f};
    float mrun[4], lrun[4];
    for (int r = 0; r < 4; ++r) { mrun[r] = -1e30f; lrun[r] = 0.f; }
    unsigned short* pl = &plds[w][0];
    int njt = (i0 + 15) / 32 + 1;
    for (int jt = 0; jt < njt; ++jt) {
        int j0 = jt * 32;
        f32x4 Sv[2];
#pragma unroll
        for (int jn = 0; jn < 2; ++jn) {
            const unsigned short* vr = vbase + (size_t)(j0 + jn * 16 + lrow) * 64 + lgrp * 8;
            bf16x8 vb0 = *reinterpret_cast<const bf16x8*>(vr);
            bf16x8 vb1 = *reinterpret_cast<const bf16x8*>(vr + 32);
            f32x4 c = (f32x4){0.f, 0.f, 0.f, 0.f};
            c = mfma16(ga0, vb0, c);
            c = mfma16(ga1, vb1, c);
            Sv[jn] = c;
        }
        if (j0 + 31 > i0) {
#pragma unroll
            for (int jn = 0; jn < 2; ++jn)
#pragma unroll
                for (int r = 0; r < 4; ++r) {
                    int ii = i0 + lgrp * 4 + r;
                    int jj = j0 + jn * 16 + lrow;
                    if (jj > ii) Sv[jn][r] = -1e30f;
                }
        }
        float sc[4];
#pragma unroll
        for (int r = 0; r < 4; ++r) {
            float t = fmaxf(Sv[0][r], Sv[1][r]);
#pragma unroll
            for (int m = 1; m < 16; m <<= 1) t = fmaxf(t, __shfl_xor(t, m));
            float mnew = fmaxf(mrun[r], t);
            sc[r] = __expf(mrun[r] - mnew);
            float p0 = __expf(Sv[0][r] - mnew);
            float p1 = __expf(Sv[1][r] - mnew);
            Sv[0][r] = p0;
            Sv[1][r] = p1;
            float s2 = p0 + p1;
#pragma unroll
            for (int m = 1; m < 16; m <<= 1) s2 += __shfl_xor(s2, m);
            lrun[r] = lrun[r] * sc[r] + s2;
            mrun[r] = mnew;
        }
#pragma unroll
        for (int n = 0; n < 4; ++n)
#pragma unroll
            for (int r = 0; r < 4; ++r) acc[n][r] *= sc[r];
#pragma unroll
        for (int r = 0; r < 4; ++r) {
            pl[(lgrp * 4 + r) * 40 + lrow] = f2bf(Sv[0][r]);
            pl[(lgrp * 4 + r) * 40 + 16 + lrow] = f2bf(Sv[1][r]);
        }
        // wave-local LDS RAW: DS ops are in-order per wave; compiler inserts lgkmcnt.
        bf16x8 pa = *reinterpret_cast<const bf16x8*>(pl + lrow * 40 + lgrp * 8);
#pragma unroll
        for (int n = 0; n < 4; ++n) {
            bf16x8 vtb = *reinterpret_cast<const bf16x8*>(tbase + (size_t)(n * 16 + lrow) * S_ + j0 + lgrp * 8);
            acc[n] = mfma16(pa, vtb, acc[n]);
        }
    }
    int b = bh >> 4, h = bh & 15;
    float rl[4];
#pragma unroll
    for (int r = 0; r < 4; ++r) rl[r] = 1.0f / lrun[r];
#pragma unroll
    for (int n = 0; n < 4; ++n)
#pragma unroll
        for (int r = 0; r < 4; ++r) {
            int ii = i0 + lgrp * 4 + r;
            int e = h * 64 + n * 16 + lrow;
            attn_out[(size_t)(b * S_ + ii) * E_ + e] = f2bf(acc[n][r] * rl[r]);
        }
}

extern "C" void kernel_launch(void* const* d_in, const int* in_sizes, int n_in,
                              void* d_out, int out_size, void* d_ws, size_t ws_size,
                              hipStream_t stream) {
    const float* x = (const float*)d_in[0];
    const float* wv_w = (const float*)d_in[1];
    const float* wv_b = (const float*)d_in[2];
    const float* wo_w = (const float*)d_in[3];
    const float* wo_b = (const float*)d_in[4];
    float* out = (float*)d_out;

    char* w = (char*)d_ws;
    unsigned short* x_bf = (unsigned short*)(w);               // 8 MB
    unsigned short* wv_bf = (unsigned short*)(w + 8388608);    // 2 MB
    unsigned short* wo_bf = (unsigned short*)(w + 10485760);   // 2 MB
    unsigned short* v_bf = (unsigned short*)(w + 12582912);    // 8 MB  [b][h][s][d]
    unsigned short* vt_bf = (unsigned short*)(w + 20971520);   // 8 MB  [b][h][d][s]
    float* invd = (float*)(w + 29360128);                      // 16 MB
    unsigned short* gene = (unsigned short*)(w + 46137344);    // 8 MB
    unsigned short* a_bf = (unsigned short*)(w + 54525952);    // 8 MB  [b][s][e]
    unsigned int* mm = (unsigned int*)(w + 62914560);          // 16 B
    if (ws_size < 62914576) return;  // insufficient workspace -> fail loudly

    k_init<<<1, 64, 0, stream>>>(mm);
    k_cast<<<2048, 256, 0, stream>>>(x, x_bf, 524288);
    k_cast<<<512, 256, 0, stream>>>(wv_w, wv_bf, 131072);
    k_cast<<<512, 256, 0, stream>>>(wo_w, wo_bf, 131072);
    k_gemm<0><<<dim3(32, 8), 256, 0, stream>>>(x_bf, wv_bf, wv_b, v_bf, nullptr, mm);
    k_transpose<<<dim3(32, 32), 256, 0, stream>>>(v_bf, vt_bf);
    k_scan<<<32, 64, 0, stream>>>(v_bf, invd, mm);
    k_rowsum<<<16384, 256, 0, stream>>>(invd, gene, mm);
    k_attn<<<1024, 256, 0, stream>>>(gene, v_bf, vt_bf, a_bf);
    k_gemm<1><<<dim3(32, 8), 256, 0, stream>>>(a_bf, wo_bf, wo_b, nullptr, out, nullptr);
}